// Round 8
// baseline (104.234 us; speedup 1.0000x reference)
//
#include <hip/hip_runtime.h>

#define D_DIM   256
#define NBLOCKS 1024          // 4 blocks/CU resident at <=128 VGPR
#define NWAVES  (NBLOCKS * 4) // 4096 waves

typedef float v4f __attribute__((ext_vector_type(4)));

__device__ __forceinline__ float dot4(v4f v, v4f w) {
    return v[0]*w[0] + v[1]*w[1] + v[2]*w[2] + v[3]*w[3];
}
__device__ __forceinline__ float sigmoidf_(float t) {
    return 1.0f / (1.0f + __expf(-t));
}
__device__ __forceinline__ v4f vzero() {
    v4f z = {0.f, 0.f, 0.f, 0.f};
    return z;
}
__device__ __forceinline__ void flush_acc(float* __restrict__ out, int b,
                                          int lane, v4f acc) {
    float* p = out + (size_t)b * D_DIM + lane * 4;
    unsafeAtomicAdd(p + 0, acc[0]);
    unsafeAtomicAdd(p + 1, acc[1]);
    unsafeAtomicAdd(p + 2, acc[2]);
    unsafeAtomicAdd(p + 3, acc[3]);
}

// quad_perm[q,q,q,q] broadcast within each 4-lane group (VALU DPP, no DS)
template<int CTRL>
__device__ __forceinline__ float qperm(float v) {
    return __int_as_float(
        __builtin_amdgcn_mov_dpp(__float_as_int(v), CTRL, 0xF, 0xF, 0));
}

// Two-level 4-row gate: 12 DS ops total (was 24) and ONE sigmoid (was 4).
// Level 1: quad-local butterfly per row. Select s_{lane&3}. Level 2: shared
// butterfly over quads -> lane class r holds row r's full dot. Sigmoid once,
// then quad_perm DPP broadcasts g0..g3 to all lanes.
__device__ __forceinline__ void gate4(float s0, float s1, float s2, float s3,
                                      bool l1, bool l2, float bias,
                                      float& g0, float& g1, float& g2, float& g3) {
    s0 += __shfl_xor(s0, 1, 64); s0 += __shfl_xor(s0, 2, 64);
    s1 += __shfl_xor(s1, 1, 64); s1 += __shfl_xor(s1, 2, 64);
    s2 += __shfl_xor(s2, 1, 64); s2 += __shfl_xor(s2, 2, 64);
    s3 += __shfl_xor(s3, 1, 64); s3 += __shfl_xor(s3, 2, 64);
    float va = l1 ? s1 : s0;
    float vb = l1 ? s3 : s2;
    float v  = l2 ? vb : va;          // v = s_{lane&3} (quad-summed)
    v += __shfl_xor(v, 4, 64);
    v += __shfl_xor(v, 8, 64);
    v += __shfl_xor(v, 16, 64);
    v += __shfl_xor(v, 32, 64);       // full row total for row lane&3
    float g = sigmoidf_(v + bias);
    g0 = qperm<0x00>(g);
    g1 = qperm<0x55>(g);
    g2 = qperm<0xAA>(g);
    g3 = qperm<0xFF>(g);
}

struct Grp { v4f c0, c1, c2, c3; };

__device__ __forceinline__ void pf(Grp& G, const float* px, bool pred) {
    if (pred) {   // wave-uniform predicate
        G.c0 = __builtin_nontemporal_load((const v4f*)(px + 0 * D_DIM));
        G.c1 = __builtin_nontemporal_load((const v4f*)(px + 1 * D_DIM));
        G.c2 = __builtin_nontemporal_load((const v4f*)(px + 2 * D_DIM));
        G.c3 = __builtin_nontemporal_load((const v4f*)(px + 3 * D_DIM));
    }
}

__device__ __forceinline__ void proc_u(const Grp& G, v4f w4, float bias,
                                       bool l1, bool l2, v4f& acc) {
    float g0, g1, g2, g3;
    gate4(dot4(G.c0, w4), dot4(G.c1, w4), dot4(G.c2, w4), dot4(G.c3, w4),
          l1, l2, bias, g0, g1, g2, g3);
    acc += G.c0 * g0 + G.c1 * g1 + G.c2 * g2 + G.c3 * g3;
}

__device__ __forceinline__ void proc_g(const Grp& G, int4 cb, v4f w4, float bias,
                                       bool l1, bool l2, v4f& acc, int& cur,
                                       float* __restrict__ out, int lane) {
    float g0, g1, g2, g3;
    gate4(dot4(G.c0, w4), dot4(G.c1, w4), dot4(G.c2, w4), dot4(G.c3, w4),
          l1, l2, bias, g0, g1, g2, g3);
    if ((cb.x == cur) & (cb.y == cur) & (cb.z == cur) & (cb.w == cur)) {
        acc += G.c0 * g0 + G.c1 * g1 + G.c2 * g2 + G.c3 * g3;
    } else {
        if (cb.x != cur) { flush_acc(out, cur, lane, acc); acc = vzero(); cur = cb.x; }
        acc += G.c0 * g0;
        if (cb.y != cur) { flush_acc(out, cur, lane, acc); acc = vzero(); cur = cb.y; }
        acc += G.c1 * g1;
        if (cb.z != cur) { flush_acc(out, cur, lane, acc); acc = vzero(); cur = cb.z; }
        acc += G.c2 * g2;
        if (cb.w != cur) { flush_acc(out, cur, lane, acc); acc = vzero(); cur = cb.w; }
        acc += G.c3 * g3;
    }
}

// 4096 waves, contiguous even split of 4-row groups (30-31/wave). Copy-free
// distance-3 pipeline (named sets A/B/C, unroll x3): ~650cy issue-to-consume
// cover, 12KB/wave in flight. Waves fully inside one segment (~55%) take a
// no-bid-load uniform path. Flush via fp32 HW atomics per (range x segment).
__global__ __launch_bounds__(256) void attentive_readout_kernel(
    const float* __restrict__ x,
    const int* __restrict__ bid,
    const float* __restrict__ gw,
    const float* __restrict__ gb,
    float* __restrict__ out,
    int n)
{
    int gtid = blockIdx.x * blockDim.x + threadIdx.x;
    int wave = gtid >> 6;
    int lane = threadIdx.x & 63;

    const int total_groups = n >> 2;          // n % 4 == 0 for this shape
    const int base = total_groups / NWAVES;
    const int rem  = total_groups % NWAVES;
    const int G0   = wave * base + (wave < rem ? wave : rem);
    const int ng   = base + (wave < rem ? 1 : 0);
    if (ng <= 0) return;

    const long long r0   = (long long)G0 << 2;
    const long long rend = r0 + ((long long)ng << 2);

    const v4f w4 = *(const v4f*)(gw + lane * 4);
    const float bias = gb[0];
    const bool l1 = lane & 1;
    const bool l2 = lane & 2;

    v4f acc = vzero();
    const int bfirst = bid[r0];
    const int blast  = bid[rend - 1];

    const float* base_px = x + (size_t)r0 * D_DIM + lane * 4;

    Grp A, B, C;
    const float* pA = base_px;
    const float* pB = base_px + 4 * D_DIM;
    const float* pC = base_px + 8 * D_DIM;

    if (bfirst == blast) {
        // ---------- uniform path: no bid loads, no compares ----------
        pf(A, pA, true);
        pf(B, pB, ng > 1);
        pf(C, pC, ng > 2);
        int g = 0;
        for (; g + 3 <= ng; g += 3) {
            proc_u(A, w4, bias, l1, l2, acc);
            pf(A, pA + 12 * D_DIM, g + 3 < ng); pA += 12 * D_DIM;
            proc_u(B, w4, bias, l1, l2, acc);
            pf(B, pB + 12 * D_DIM, g + 4 < ng); pB += 12 * D_DIM;
            proc_u(C, w4, bias, l1, l2, acc);
            pf(C, pC + 12 * D_DIM, g + 5 < ng); pC += 12 * D_DIM;
        }
        if (g < ng)     proc_u(A, w4, bias, l1, l2, acc);
        if (g + 1 < ng) proc_u(B, w4, bias, l1, l2, acc);
        flush_acc(out, bfirst, lane, acc);
    } else {
        // ---------- general path: batched int4 bid checks ----------
        int cur = bfirst;
        const int* qA = bid + r0;
        const int* qB = qA + 4;
        const int* qC = qA + 8;
        int4 ab, bb, cb;
        pf(A, pA, true);            ab = *(const int4*)qA;
        pf(B, pB, ng > 1); if (ng > 1) bb = *(const int4*)qB;
        pf(C, pC, ng > 2); if (ng > 2) cb = *(const int4*)qC;
        int g = 0;
        for (; g + 3 <= ng; g += 3) {
            proc_g(A, ab, w4, bias, l1, l2, acc, cur, out, lane);
            pf(A, pA + 12 * D_DIM, g + 3 < ng);
            if (g + 3 < ng) ab = *(const int4*)(qA + 12);
            pA += 12 * D_DIM; qA += 12;

            proc_g(B, bb, w4, bias, l1, l2, acc, cur, out, lane);
            pf(B, pB + 12 * D_DIM, g + 4 < ng);
            if (g + 4 < ng) bb = *(const int4*)(qB + 12);
            pB += 12 * D_DIM; qB += 12;

            proc_g(C, cb, w4, bias, l1, l2, acc, cur, out, lane);
            pf(C, pC + 12 * D_DIM, g + 5 < ng);
            if (g + 5 < ng) cb = *(const int4*)(qC + 12);
            pC += 12 * D_DIM; qC += 12;
        }
        if (g < ng)     proc_g(A, ab, w4, bias, l1, l2, acc, cur, out, lane);
        if (g + 1 < ng) proc_g(B, bb, w4, bias, l1, l2, acc, cur, out, lane);
        flush_acc(out, cur, lane, acc);
    }
}

extern "C" void kernel_launch(void* const* d_in, const int* in_sizes, int n_in,
                              void* d_out, int out_size, void* d_ws, size_t ws_size,
                              hipStream_t stream) {
    const float* x   = (const float*)d_in[0];
    const int*   bid = (const int*)d_in[1];   // int32 per harness contract
    const float* gw  = (const float*)d_in[3];
    const float* gb  = (const float*)d_in[4];
    float*       out = (float*)d_out;

    const int n = in_sizes[0] / D_DIM;   // 500000 (divisible by 4)

    // d_out is poisoned (0xAA) once and never re-poisoned: zero every call.
    hipMemsetAsync(d_out, 0, (size_t)out_size * sizeof(float), stream);

    attentive_readout_kernel<<<NBLOCKS, 256, 0, stream>>>(
        x, bid, gw, gb, out, n);
}

// Round 9
// 98.106 us; speedup vs baseline: 1.0625x; 1.0625x over previous
//
#include <hip/hip_runtime.h>

#define D_DIM   256
#define NBLOCKS 1024          // 4 blocks/CU: resident even at <=128 VGPR
#define NWAVES  (NBLOCKS * 4) // 4096 waves

typedef float v4f __attribute__((ext_vector_type(4)));

__device__ __forceinline__ float dot4(v4f v, v4f w) {
    return v[0]*w[0] + v[1]*w[1] + v[2]*w[2] + v[3]*w[3];
}
__device__ __forceinline__ float sigmoidf_(float t) {
    return 1.0f / (1.0f + __expf(-t));
}
__device__ __forceinline__ v4f vzero() {
    v4f z = {0.f, 0.f, 0.f, 0.f};
    return z;
}
__device__ __forceinline__ void flush_acc(float* __restrict__ out, int b,
                                          int lane, v4f acc) {
    float* p = out + (size_t)b * D_DIM + lane * 4;
    unsafeAtomicAdd(p + 0, acc[0]);
    unsafeAtomicAdd(p + 1, acc[1]);
    unsafeAtomicAdd(p + 2, acc[2]);
    unsafeAtomicAdd(p + 3, acc[3]);
}

__device__ __forceinline__ void prefetch_group(v4f& c0, v4f& c1, v4f& c2, v4f& c3,
                                               int4& cb,
                                               const float* px, const int* pb,
                                               bool pred) {
    if (pred) {   // wave-uniform predicate
        c0 = __builtin_nontemporal_load((const v4f*)(px + 0 * D_DIM));
        c1 = __builtin_nontemporal_load((const v4f*)(px + 1 * D_DIM));
        c2 = __builtin_nontemporal_load((const v4f*)(px + 2 * D_DIM));
        c3 = __builtin_nontemporal_load((const v4f*)(px + 3 * D_DIM));
        cb = *(const int4*)pb;      // 16B-aligned: group start % 4 == 0
    }
}

__device__ __forceinline__ void process_group(v4f c0, v4f c1, v4f c2, v4f c3,
                                              int4 cb, v4f w4, float bias,
                                              v4f& acc, int& cur,
                                              float* __restrict__ out, int lane) {
    // Four INDEPENDENT 6-deep butterfly chains — they interleave in the
    // scheduler; do not share/serialize them (round-8 lesson: a merged
    // two-level reduce lengthened the critical path and regressed 5.7%).
    float s0 = dot4(c0, w4);
    float s1 = dot4(c1, w4);
    float s2 = dot4(c2, w4);
    float s3 = dot4(c3, w4);
    #pragma unroll
    for (int off = 32; off > 0; off >>= 1) {
        s0 += __shfl_xor(s0, off, 64);
        s1 += __shfl_xor(s1, off, 64);
        s2 += __shfl_xor(s2, off, 64);
        s3 += __shfl_xor(s3, off, 64);
    }
    float g0 = sigmoidf_(s0 + bias);
    float g1 = sigmoidf_(s1 + bias);
    float g2 = sigmoidf_(s2 + bias);
    float g3 = sigmoidf_(s3 + bias);

    if ((cb.x == cur) & (cb.y == cur) & (cb.z == cur) & (cb.w == cur)) {
        acc += c0 * g0 + c1 * g1 + c2 * g2 + c3 * g3;   // common case
    } else {
        if (cb.x != cur) { flush_acc(out, cur, lane, acc); acc = vzero(); cur = cb.x; }
        acc += c0 * g0;
        if (cb.y != cur) { flush_acc(out, cur, lane, acc); acc = vzero(); cur = cb.y; }
        acc += c1 * g1;
        if (cb.z != cur) { flush_acc(out, cur, lane, acc); acc = vzero(); cur = cb.z; }
        acc += c2 * g2;
        if (cb.w != cur) { flush_acc(out, cur, lane, acc); acc = vzero(); cur = cb.w; }
        acc += c3 * g3;
    }
}

// 4096 waves (1024 blocks = 4/CU, resident at any plausible VGPR count —
// no second scheduling round). The 125000 4-row groups are split
// contiguously and evenly (30 or 31 per wave, <=1.6% skew). Within a wave:
// copy-free distance-2 pipeline over groups (two named buffer sets, loop
// unrolled x2) — 8KB/wave in flight, counted vmcnt waits. Flush via fp32
// HW atomics once per (range x segment).
__global__ __launch_bounds__(256) void attentive_readout_kernel(
    const float* __restrict__ x,
    const int* __restrict__ bid,
    const float* __restrict__ gw,
    const float* __restrict__ gb,
    float* __restrict__ out,
    int n)
{
    int gtid = blockIdx.x * blockDim.x + threadIdx.x;
    int wave = gtid >> 6;
    int lane = threadIdx.x & 63;

    const int total_groups = n >> 2;            // n % 4 == 0 for this shape
    const int base = total_groups / NWAVES;
    const int rem  = total_groups % NWAVES;
    const int g0   = wave * base + (wave < rem ? wave : rem);
    const int ng   = base + (wave < rem ? 1 : 0);
    if (ng <= 0) return;

    const long long r0 = (long long)g0 << 2;

    const v4f w4 = *(const v4f*)(gw + lane * 4);
    const float bias = gb[0];

    v4f acc = vzero();
    int cur = bid[r0];

    const float* pxa = x + (size_t)r0 * D_DIM + lane * 4;
    const float* pxb = pxa + 4 * D_DIM;
    const int*   pba = bid + r0;
    const int*   pbb = pba + 4;

    v4f a0, a1, a2, a3, b0, b1, b2, b3;
    int4 ab, bb;
    prefetch_group(a0, a1, a2, a3, ab, pxa, pba, true);
    prefetch_group(b0, b1, b2, b3, bb, pxb, pbb, ng > 1);

    int g = 0;
    for (; g + 2 <= ng; g += 2) {
        process_group(a0, a1, a2, a3, ab, w4, bias, acc, cur, out, lane);
        prefetch_group(a0, a1, a2, a3, ab, pxa + 8 * D_DIM, pba + 8,
                       g + 2 < ng);
        pxa += 8 * D_DIM; pba += 8;

        process_group(b0, b1, b2, b3, bb, w4, bias, acc, cur, out, lane);
        prefetch_group(b0, b1, b2, b3, bb, pxb + 8 * D_DIM, pbb + 8,
                       g + 3 < ng);
        pxb += 8 * D_DIM; pbb += 8;
    }
    if (g < ng) {   // odd leftover group lives in A
        process_group(a0, a1, a2, a3, ab, w4, bias, acc, cur, out, lane);
    }

    flush_acc(out, cur, lane, acc);
}

extern "C" void kernel_launch(void* const* d_in, const int* in_sizes, int n_in,
                              void* d_out, int out_size, void* d_ws, size_t ws_size,
                              hipStream_t stream) {
    const float* x   = (const float*)d_in[0];
    const int*   bid = (const int*)d_in[1];   // int32 per harness contract
    const float* gw  = (const float*)d_in[3];
    const float* gb  = (const float*)d_in[4];
    float*       out = (float*)d_out;

    const int n = in_sizes[0] / D_DIM;   // 500000

    // d_out is poisoned (0xAA) once and never re-poisoned: zero every call.
    hipMemsetAsync(d_out, 0, (size_t)out_size * sizeof(float), stream);

    attentive_readout_kernel<<<NBLOCKS, 256, 0, stream>>>(
        x, bid, gw, gb, out, n);
}